// Round 1
// 2280.326 us; speedup vs baseline: 1.0348x; 1.0348x over previous
//
#include <hip/hip_runtime.h>
#include <hip/hip_bf16.h>
#include <math.h>

#define BB 2
#define SS 1024
#define DD 1024
#define NHEAD 16
#define HDIM 64
#define NLAYER 6
#define VOCAB 50257
#define DFF 4096
#define BS 2048

typedef __bf16 bf16_t;
typedef __attribute__((ext_vector_type(8))) __bf16 bf16x8;
typedef __attribute__((ext_vector_type(4))) __bf16 bf16x4;
typedef __attribute__((ext_vector_type(4))) float f32x4;

__device__ __forceinline__ f32x4 mfma16(bf16x8 a, bf16x8 b, f32x4 c) {
  return __builtin_amdgcn_mfma_f32_16x16x32_bf16(a, b, c, 0, 0, 0);
}

__device__ __forceinline__ void async16(const void* gp, void* lp) {
  __builtin_amdgcn_global_load_lds(
      (const __attribute__((address_space(1))) unsigned int*)gp,
      (__attribute__((address_space(3))) unsigned int*)lp, 16, 0, 0);
}

__device__ __forceinline__ f32x4 zero4() {
  f32x4 v = {0.f, 0.f, 0.f, 0.f};
  return v;
}

// ---------------- embedding: x = tok_emb[tok] + pos_emb[s] ----------------
__global__ void k_embed(const int* __restrict__ tokens, const float* __restrict__ tok_emb,
                        const float* __restrict__ pos_emb, float* __restrict__ x) {
  int row = blockIdx.x;           // 0..BS-1
  int s = row & (SS - 1);
  int tk = tokens[row];
  const float4* te = (const float4*)(tok_emb + (size_t)tk * DD);
  const float4* pe = (const float4*)(pos_emb + (size_t)s * DD);
  float4* xo = (float4*)(x + (size_t)row * DD);
  int i = threadIdx.x;            // 256 threads, DD/4 = 256
  float4 a = te[i], b = pe[i];
  xo[i] = make_float4(a.x + b.x, a.y + b.y, a.z + b.z, a.w + b.w);
}

// ---------------- f32 -> bf16 elementwise (tok_emb) ----------------
__global__ void k_cvt(const float* __restrict__ in, bf16_t* __restrict__ out, long n4) {
  long i = (long)blockIdx.x * blockDim.x + threadIdx.x;
  long stride = (long)gridDim.x * blockDim.x;
  for (; i < n4; i += stride) {
    float4 v = ((const float4*)in)[i];
    bf16x4 o;
    o.x = (bf16_t)v.x; o.y = (bf16_t)v.y; o.z = (bf16_t)v.z; o.w = (bf16_t)v.w;
    ((bf16x4*)out)[i] = o;
  }
}

// ---------------- merged per-layer weight transpose+cvt ----------------
// blocks [0,4096): wq/wk/wv/wo (DD x DD, 1024 tiles each)
// blocks [4096,8192): w1 (DD x DFF), [8192,12288): w2 (DFF x DD)
__global__ void k_trans_all(const float* __restrict__ wq, const float* __restrict__ wk,
                            const float* __restrict__ wv, const float* __restrict__ wo,
                            const float* __restrict__ w1, const float* __restrict__ w2,
                            bf16_t* __restrict__ wqkvt, bf16_t* __restrict__ wot,
                            bf16_t* __restrict__ w1t, bf16_t* __restrict__ w2t) {
  __shared__ float tile[32][33];
  int blk = blockIdx.x;
  const float* in;
  bf16_t* out;
  int K, N, tl;
  if (blk < 4096) {
    int m = blk >> 10;
    tl = blk & 1023;
    K = DD; N = DD;
    in = (m == 0) ? wq : (m == 1) ? wk : (m == 2) ? wv : wo;
    out = (m == 3) ? wot : wqkvt + (size_t)m * DD * DD;
  } else if (blk < 8192) {
    tl = blk - 4096; in = w1; out = w1t; K = DD; N = DFF;
  } else {
    tl = blk - 8192; in = w2; out = w2t; K = DFF; N = DD;
  }
  int ntile = N >> 5;
  int nt = tl % ntile, kt = tl / ntile;
  int t = threadIdx.x, tx = t & 31, ty = t >> 5;
  const float* ip = in + (size_t)(kt * 32) * N + nt * 32;
#pragma unroll
  for (int u = 0; u < 4; u++) tile[ty + 8 * u][tx] = ip[(size_t)(ty + 8 * u) * N + tx];
  __syncthreads();
  bf16_t* op = out + (size_t)(nt * 32) * K + kt * 32;
#pragma unroll
  for (int u = 0; u < 4; u++) op[(size_t)(ty + 8 * u) * K + tx] = (bf16_t)tile[tx][ty + 8 * u];
}

// ---------------- V transpose: qkv[:, 2D + h*64 + d] -> vt[b][h][d][s] ----------------
__global__ void k_vtrans(const bf16_t* __restrict__ qkv, bf16_t* __restrict__ vt) {
  __shared__ bf16_t tile[32][33];
  int t = threadIdx.x, tx = t & 31, ty = t >> 5;
  int blk = blockIdx.x;
  int dt = blk & 1;  blk >>= 1;
  int st = blk & 31; blk >>= 5;
  int h  = blk & 15; blk >>= 4;
  int b  = blk;
  const bf16_t* ip = qkv + (size_t)(b * SS + st * 32) * (3 * DD) + 2 * DD + h * HDIM + dt * 32;
#pragma unroll
  for (int u = 0; u < 4; u++) tile[ty + 8 * u][tx] = ip[(size_t)(ty + 8 * u) * (3 * DD) + tx];
  __syncthreads();
  bf16_t* op = vt + ((size_t)((b * NHEAD + h) * HDIM + dt * 32)) * SS + st * 32;
#pragma unroll
  for (int u = 0; u < 4; u++) op[(size_t)(ty + 8 * u) * SS + tx] = tile[tx][ty + 8 * u];
}

// ---------------- LayerNorm: f32 in -> bf16 out ----------------
__global__ void k_ln(const float* __restrict__ x, const float* __restrict__ g,
                     const float* __restrict__ b, bf16_t* __restrict__ out) {
  int row = blockIdx.x, t = threadIdx.x;
  float4 v = ((const float4*)(x + (size_t)row * DD))[t];
  float s = v.x + v.y + v.z + v.w;
  float s2 = v.x * v.x + v.y * v.y + v.z * v.z + v.w * v.w;
#pragma unroll
  for (int m = 32; m >= 1; m >>= 1) { s += __shfl_xor(s, m); s2 += __shfl_xor(s2, m); }
  __shared__ float red[8];
  int w = t >> 6;
  if ((t & 63) == 0) { red[w] = s; red[4 + w] = s2; }
  __syncthreads();
  s = red[0] + red[1] + red[2] + red[3];
  s2 = red[4] + red[5] + red[6] + red[7];
  float mean = s * (1.f / DD);
  float var = s2 * (1.f / DD) - mean * mean;
  float r = rsqrtf(var + 1e-5f);
  float4 gg = ((const float4*)g)[t], bb = ((const float4*)b)[t];
  bf16x4 o;
  o.x = (bf16_t)((v.x - mean) * r * gg.x + bb.x);
  o.y = (bf16_t)((v.y - mean) * r * gg.y + bb.y);
  o.z = (bf16_t)((v.z - mean) * r * gg.z + bb.z);
  o.w = (bf16_t)((v.w - mean) * r * gg.w + bb.w);
  ((bf16x4*)(out + (size_t)row * DD))[t] = o;
}

// ---------------- NT GEMM (m97 structure) for the layer GEMMs ----------------
// MODE 0: Cb = acc (bf16)
// MODE 1: Cf = acc + res
// MODE 2: Cb = gelu(acc + bias[n]) (bf16)
// MODE 3: Cf = acc + bias[n] + res
template <int MODE, bool NB>
__global__ __launch_bounds__(256, 2)
void k_gemm(const bf16_t* __restrict__ A, const bf16_t* __restrict__ Bt,
            int M, int N, int K,
            float* __restrict__ Cf, bf16_t* __restrict__ Cb,
            const float* __restrict__ bias, const float* __restrict__ res) {
  __shared__ bf16_t lA[128 * 32];
  __shared__ bf16_t lB[128 * 32];
  int t = threadIdx.x;
  int m0 = blockIdx.x * 128, n0 = blockIdx.y * 128;
  int lane = t & 63, wvid = t >> 6;
  int wy = wvid >> 1, wx = wvid & 1;
  int lo = lane & 15, hi = lane >> 4;
  f32x4 acc[4][4];
#pragma unroll
  for (int i = 0; i < 4; i++)
#pragma unroll
    for (int j = 0; j < 4; j++) acc[i][j] = zero4();

  int arow = t >> 2;
  int acol = (t & 3) * 8;
  const bf16_t* ap = A + (size_t)(m0 + arow) * K + acol;
  int br0 = n0 + arow, br1 = br0 + 64;
  if (NB) { br0 = min(br0, N - 1); br1 = min(br1, N - 1); }
  const bf16_t* bp0 = Bt + (size_t)br0 * K + acol;
  const bf16_t* bp1 = Bt + (size_t)br1 * K + acol;

  for (int k0 = 0; k0 < K; k0 += 32) {
    async16(ap, &lA[t * 8]);
    async16(ap + (size_t)64 * K, &lA[2048 + t * 8]);
    async16(bp0, &lB[t * 8]);
    async16(bp1, &lB[2048 + t * 8]);
    __syncthreads();
    int kc = hi * 8;
    bf16x8 af[4], bfr[4];
#pragma unroll
    for (int i = 0; i < 4; i++) af[i] = *(const bf16x8*)&lA[(64 * wy + 16 * i + lo) * 32 + kc];
#pragma unroll
    for (int j = 0; j < 4; j++) bfr[j] = *(const bf16x8*)&lB[(64 * wx + 16 * j + lo) * 32 + kc];
#pragma unroll
    for (int i = 0; i < 4; i++)
#pragma unroll
      for (int j = 0; j < 4; j++) acc[i][j] = mfma16(af[i], bfr[j], acc[i][j]);
    __syncthreads();
    ap += 32; bp0 += 32; bp1 += 32;
  }

#pragma unroll
  for (int i = 0; i < 4; i++) {
#pragma unroll
    for (int j = 0; j < 4; j++) {
#pragma unroll
      for (int r = 0; r < 4; r++) {
        int mm = m0 + 64 * wy + 16 * i + 4 * hi + r;
        int nn = n0 + 64 * wx + 16 * j + lo;
        float v = acc[i][j][r];
        size_t idx = (size_t)mm * N + nn;
        if constexpr (MODE == 0) {
          Cb[idx] = (bf16_t)v;
        } else if constexpr (MODE == 1) {
          Cf[idx] = v + res[idx];
        } else if constexpr (MODE == 2) {
          float xx = v + bias[nn];
          Cb[idx] = (bf16_t)(0.5f * xx * (1.f + erff(xx * 0.7071067811865475f)));
        } else if constexpr (MODE == 3) {
          Cf[idx] = v + bias[nn] + res[idx];
        } else {
          if (nn < N) Cf[idx] = v;
        }
      }
    }
  }
}

// ================= 256x256 8-phase logits GEMM (T1+T2+T3+T4+T5) =================
// C[M=2048, N=VOCAB] = A[2048,1024] @ Bt[VOCAB,1024]^T, f32 out, N guarded.
// 8 waves (2Mx4N), BK=64, 2 LDS buffers x 2 halves per operand (128 KiB total).
// LDS layout: row-major [128][64] per half with XOR swizzle col16 ^= (row&7),
// applied on the global SOURCE address (linear global_load_lds dest) and on
// the ds_read address (rule 21: both-sides-or-neither).

#define NBLK_LOG ((VOCAB + 255) / 256)   // 197; 8*197 = 1576 % 8 == 0 -> simple XCD swizzle OK

#define A_LDSOFF(d, h) ((d) * 16384 + (h) * 8192)
#define B_LDSOFF(d, h) (32768 + (d) * 16384 + (h) * 8192)

__global__ __launch_bounds__(512, 2)
void k_gemm_logits(const bf16_t* __restrict__ A, const bf16_t* __restrict__ Bt,
                   float* __restrict__ C) {
  constexpr int KD = DD;        // 1024
  constexpr int N  = VOCAB;
  constexpr int NT = KD / 64;   // 16 K-tiles, 8 iterations
  __shared__ bf16_t sm[65536];  // 128 KiB

  int t = threadIdx.x;
  int lane = t & 63, w = t >> 6;
  int lo = lane & 15, hi = lane >> 4;
  int wm = w >> 2, wn = w & 3;
  int bh = wn >> 1;

  // T1: bijective XCD swizzle (dispatch d -> XCD d%8; give each XCD a contiguous tile chunk)
  int dlin = blockIdx.y * 8 + blockIdx.x;
  int tt = (dlin & 7) * NBLK_LOG + (dlin >> 3);
  int m0 = (tt & 7) * 256;
  int n0 = (tt >> 3) * 256;

  // ---- staging addresses (pre-swizzled global source, linear LDS dest) ----
  int srow = (w << 4) + (lane >> 3);              // q=0 row within half: w*16 + l/8
  int scol = ((lane & 7) ^ (lane >> 3)) << 3;     // swizzled col (elements)
  size_t a_off0 = (size_t)(m0 + srow) * KD + scol;
  size_t a_off1 = a_off0 + (size_t)8 * KD;
  size_t b_off00, b_off01, b_off10, b_off11;
  {
    int r0 = min(n0 + srow,       N - 1);
    int r1 = min(n0 + srow + 8,   N - 1);
    int r2 = min(n0 + 128 + srow,     N - 1);
    int r3 = min(n0 + 128 + srow + 8, N - 1);
    b_off00 = (size_t)r0 * KD + scol;
    b_off01 = (size_t)r1 * KD + scol;
    b_off10 = (size_t)r2 * KD + scol;
    b_off11 = (size_t)r3 * KD + scol;
  }
  int c0 = (w * 2) * 512 + lane * 8;   // LDS chunk offset (elements), q=0
  int c1 = c0 + 512;

#define STAGE_A(d, h, tl)                                                             \
  async16(A + a_off0 + (size_t)(h) * (128 * KD) + (tl) * 64, &sm[A_LDSOFF(d, h) + c0]); \
  async16(A + a_off1 + (size_t)(h) * (128 * KD) + (tl) * 64, &sm[A_LDSOFF(d, h) + c1]);
#define STAGE_B(d, h, tl)                                                             \
  async16(Bt + b_off##h##0 + (tl) * 64, &sm[B_LDSOFF(d, h) + c0]);                    \
  async16(Bt + b_off##h##1 + (tl) * 64, &sm[B_LDSOFF(d, h) + c1]);

  // ---- ds_read bases (swizzled) ----
  int su0 = (hi ^ (lo & 7)) << 3;          // kk=0: col16 = hi
  int su1 = ((4 + hi) ^ (lo & 7)) << 3;    // kk=1: col16 = 4+hi
  const bf16_t* aR0 = &sm[A_LDSOFF(0, 0) + wm * 8192 + lo * 64];
  const bf16_t* aR1 = &sm[A_LDSOFF(1, 0) + wm * 8192 + lo * 64];
  const bf16_t* bR0 = &sm[B_LDSOFF(0, 0) + bh * 8192 + ((wn & 1) * 64 + lo) * 64];
  const bf16_t* bR1 = &sm[B_LDSOFF(1, 0) + bh * 8192 + ((wn & 1) * 64 + lo) * 64];

#define LOAD_A4(AR, ROFF)                                            \
  _Pragma("unroll") for (int i = 0; i < 4; i++) {                    \
    a[i][0] = *(const bf16x8*)&AR[(ROFF) + i * 1024 + su0];          \
    a[i][1] = *(const bf16x8*)&AR[(ROFF) + i * 1024 + su1];          \
  }
#define LOAD_B2(BR, DST, NOFF)                                       \
  _Pragma("unroll") for (int j = 0; j < 2; j++) {                    \
    DST[j][0] = *(const bf16x8*)&BR[(NOFF) + j * 1024 + su0];        \
    DST[j][1] = *(const bf16x8*)&BR[(NOFF) + j * 1024 + su1];        \
  }
#define MFMA_Q(I0, J0, BF)                                                              \
  __builtin_amdgcn_s_setprio(1);                                                        \
  _Pragma("unroll") for (int kk = 0; kk < 2; kk++)                                      \
  _Pragma("unroll") for (int i = 0; i < 4; i++)                                         \
  _Pragma("unroll") for (int j = 0; j < 2; j++)                                         \
    acc[(I0) + i][(J0) + j] = mfma16(a[i][kk], BF[j][kk], acc[(I0) + i][(J0) + j]);     \
  __builtin_amdgcn_s_setprio(0);
#define BARR __builtin_amdgcn_s_barrier()
#define LGKM0 do { asm volatile("s_waitcnt lgkmcnt(0)" ::: "memory");                   \
                   __builtin_amdgcn_sched_barrier(0); } while (0)
#define VMC4 asm volatile("s_waitcnt vmcnt(4)" ::: "memory")

  bf16x8 a[4][2], b0[2][2], b1[2][2];
  f32x4 acc[8][4];
#pragma unroll
  for (int i = 0; i < 8; i++)
#pragma unroll
    for (int j = 0; j < 4; j++) acc[i][j] = zero4();

  // prologue: tile0 (all 4 halves -> buf0), tile1 B halves -> buf1
  STAGE_A(0, 0, 0); STAGE_A(0, 1, 0); STAGE_B(0, 0, 0); STAGE_B(0, 1, 0);
  STAGE_B(1, 0, 1); STAGE_B(1, 1, 1);
  VMC4;   // tile0 landed (tile1 B halves may be outstanding)
  BARR;

  for (int it = 0; it < NT / 2; ++it) {
    int T = 2 * it;
    int tp2 = min(T + 2, NT - 1);   // clamped restage on last iter: dead data, safe
    int tp3 = min(T + 3, NT - 1);

    // ---- P1: tile T (buf0) q0 = a(m0-3) x b0(n0-1) ----
    LOAD_A4(aR0, 0);
    LOAD_B2(bR0, b0, 0);
    STAGE_A(1, 0, T + 1);
    BARR; LGKM0;
    MFMA_Q(0, 0, b0);
    BARR;
    // ---- P2: q1 = a(m0-3) x b1(n2-3) ----
    LOAD_B2(bR0, b1, 2048);
    STAGE_A(1, 1, T + 1);
    BARR; LGKM0;
    MFMA_Q(0, 2, b1);
    BARR;
    // ---- P3: q2 = a(m4-7) x b1 ----
    LOAD_A4(aR0, 4096);
    STAGE_B(0, 0, tp2);
    BARR; LGKM0;
    MFMA_Q(4, 2, b1);
    BARR;
    // ---- P4: q3 = a(m4-7) x b0 ----
    STAGE_B(0, 1, tp2);
    BARR;
    MFMA_Q(4, 0, b0);
    VMC4;   // tile T+1 fully landed
    BARR;

    // ---- P5: tile T+1 (buf1) q0 ----
    LOAD_A4(aR1, 0);
    LOAD_B2(bR1, b0, 0);
    STAGE_A(0, 0, tp2);
    BARR; LGKM0;
    MFMA_Q(0, 0, b0);
    BARR;
    // ---- P6: q1 ----
    LOAD_B2(bR1, b1, 2048);
    STAGE_A(0, 1, tp2);
    BARR; LGKM0;
    MFMA_Q(0, 2, b1);
    BARR;
    // ---- P7: q2 ----
    LOAD_A4(aR1, 4096);
    STAGE_B(1, 0, tp3);
    BARR; LGKM0;
    MFMA_Q(4, 2, b1);
    BARR;
    // ---- P8: q3 ----
    STAGE_B(1, 1, tp3);
    BARR;
    MFMA_Q(4, 0, b0);
    VMC4;   // tile T+2 fully landed
    BARR;
  }

  // epilogue: C/D layout col=lane&15, row=hi*4+r
  float* Cw = C + (size_t)(m0 + wm * 128) * N + n0 + wn * 64;
  int ncol0 = n0 + wn * 64;
#pragma unroll
  for (int i = 0; i < 8; i++)
#pragma unroll
    for (int j = 0; j < 4; j++)
#pragma unroll
      for (int r = 0; r < 4; r++) {
        int gr = i * 16 + hi * 4 + r;
        int gc = j * 16 + lo;
        if (ncol0 + gc < N) Cw[(size_t)gr * N + gc] = acc[i][j][r];
      }

#undef STAGE_A
#undef STAGE_B
#undef LOAD_A4
#undef LOAD_B2
#undef MFMA_Q
#undef BARR
#undef LGKM0
#undef VMC4
}

// ---------------- flash attention (causal), 1 block per (b,h,128-row q tile) ----------------
__global__ __launch_bounds__(256, 1)
void k_attn(const bf16_t* __restrict__ qkv, const bf16_t* __restrict__ vt,
            bf16_t* __restrict__ o) {
  __shared__ bf16_t lQ[128 * 72];
  __shared__ bf16_t lK[64 * 72];
  __shared__ bf16_t lV[64 * 72];
  __shared__ bf16_t lP[128 * 72];
  int t = threadIdx.x;
  int lane = t & 63, w = t >> 6;
  int lo = lane & 15, hi = lane >> 4;
  int blk = blockIdx.x;
  int qt = blk & 7, h = (blk >> 3) & 15, b = blk >> 7;
  int q0 = qt * 128;
  const bf16_t* qbase = qkv + (size_t)(b * SS) * (3 * DD) + h * HDIM;
  const bf16_t* kbase = qbase + DD;
  const bf16_t* vbase = vt + (size_t)((b * NHEAD + h) * HDIM) * SS;

  // stage Q tile [128][64] into lQ (stride 72)
#pragma unroll
  for (int u = 0; u < 4; u++) {
    int c = t + 256 * u;
    int row = c >> 3, col = (c & 7) * 8;
    *(bf16x8*)&lQ[row * 72 + col] = *(const bf16x8*)&qbase[(size_t)(q0 + row) * (3 * DD) + col];
  }

  f32x4 acc_o[2][4];
#pragma unroll
  for (int i2 = 0; i2 < 2; i2++)
#pragma unroll
    for (int j2 = 0; j2 < 4; j2++) acc_o[i2][j2] = zero4();
  float mrow[8], lrow[8];
#pragma unroll
  for (int r = 0; r < 8; r++) { mrow[r] = -1e30f; lrow[r] = 0.f; }

  int nkt = 2 * qt + 2;
  for (int kt = 0; kt < nkt; kt++) {
    int k0 = kt * 64;
    __syncthreads();   // previous iteration's reads of lK/lV complete
    // stage K tile [64][64]
#pragma unroll
    for (int u = 0; u < 2; u++) {
      int c = t + 256 * u;
      int row = c >> 3, col = (c & 7) * 8;
      *(bf16x8*)&lK[row * 72 + col] = *(const bf16x8*)&kbase[(size_t)(k0 + row) * (3 * DD) + col];
    }
    // stage V tile [64 d][64 s]
#pragma unroll
    for (int u = 0; u < 2; u++) {
      int c = t + 256 * u;
      int row = c >> 3, col = (c & 7) * 8;
      *(bf16x8*)&lV[row * 72 + col] = *(const bf16x8*)&vbase[(size_t)row * SS + k0 + col];
    }
    __syncthreads();

    // S = Q K^T : wave w owns rows 32w..32w+31, all 64 cols
    f32x4 sa[2][4];
#pragma unroll
    for (int i2 = 0; i2 < 2; i2++)
#pragma unroll
      for (int j = 0; j < 4; j++) sa[i2][j] = zero4();
#pragma unroll
    for (int kk = 0; kk < 2; kk++) {
      int kc = kk * 32 + hi * 8;
      bf16x8 a0 = *(const bf16x8*)&lQ[(32 * w + lo) * 72 + kc];
      bf16x8 a1 = *(const bf16x8*)&lQ[(32 * w + 16 + lo) * 72 + kc];
#pragma unroll
      for (int j = 0; j < 4; j++) {
        bf16x8 bb = *(const bf16x8*)&lK[(16 * j + lo) * 72 + kc];
        sa[0][j] = mfma16(a0, bb, sa[0][j]);
        sa[1][j] = mfma16(a1, bb, sa[1][j]);
      }
    }

    bool diag = (kt >= 2 * qt);
#pragma unroll
    for (int i2 = 0; i2 < 2; i2++) {
#pragma unroll
      for (int r = 0; r < 4; r++) {
        int ridx = i2 * 4 + r;
        int lrow_i = 32 * w + 16 * i2 + 4 * hi + r;
        int grow = q0 + lrow_i;
        float vals[4];
        float mx = -1e30f;
#pragma unroll
        for (int j = 0; j < 4; j++) {
          float sv = sa[i2][j][r] * 0.125f;
          if (diag && (k0 + 16 * j + lo > grow)) sv = -1e30f;
          vals[j] = sv;
          mx = fmaxf(mx, sv);
        }
#pragma unroll
        for (int mk = 8; mk >= 1; mk >>= 1) mx = fmaxf(mx, __shfl_xor(mx, mk));
        float mo = mrow[ridx];
        float mn = fmaxf(mo, mx);
        float al = __expf(mo - mn);
        float ps = 0.f;
#pragma unroll
        for (int j = 0; j < 4; j++) {
          float pv = __expf(vals[j] - mn);
          ps += pv;
          lP[lrow_i * 72 + 16 * j + lo] = (bf16_t)pv;
        }
#pragma unroll
        for (int mk = 8; mk >= 1; mk >>= 1) ps += __shfl_xor(ps, mk);
        mrow[ridx] = mn;
        lrow[ridx] = lrow[ridx] * al + ps;
#pragma unroll
        for (int j2 = 0; j2 < 4; j2++) acc_o[i2][j2][r] *= al;
      }
    }
    __syncthreads();   // P writes visible (paranoia; P is wave-private)

    // O += P V : k-dim = 64 (this tile)
#pragma unroll
    for (int kk = 0; kk < 2; kk++) {
      int kc = kk * 32 + hi * 8;
      bf16x8 p0 = *(const bf16x8*)&lP[(32 * w + lo) * 72 + kc];
      bf16x8 p1 = *(const bf16x8*)&lP[(32 * w + 16 + lo) * 72 + kc];
#pragma unroll
      for (int j2 = 0; j2 < 4; j2++) {
        bf16x8 vb = *(const bf16x8*)&lV[(16 * j2 + lo) * 72 + kc];
        acc_o[0][j2] = mfma16(p0, vb, acc_o[0][j2]);
        acc_o[1][j2] = mfma16(p1, vb, acc_o[1][j2]);
      }
    }
  }

  bf16_t* obase = o + (size_t)(b * SS + q0) * DD + h * HDIM;
#pragma unroll
  for (int i2 = 0; i2 < 2; i2++) {
#pragma unroll
    for (int r = 0; r < 4; r++) {
      float inv = 1.f / lrow[i2 * 4 + r];
      int row = 32 * w + 16 * i2 + 4 * hi + r;
#pragma unroll
      for (int j2 = 0; j2 < 4; j2++)
        obase[(size_t)row * DD + 16 * j2 + lo] = (bf16_t)(acc_o[i2][j2][r] * inv);
    }
  }
}

extern "C" void kernel_launch(void* const* d_in, const int* in_sizes, int n_in,
                              void* d_out, int out_size, void* d_ws, size_t ws_size,
                              hipStream_t stream) {
  const int*   tokens  = (const int*)d_in[0];
  const float* tok_emb = (const float*)d_in[1];
  const float* pos_emb = (const float*)d_in[2];
  const float* ln1_g   = (const float*)d_in[3];
  const float* ln1_b   = (const float*)d_in[4];
  const float* wq      = (const float*)d_in[5];
  const float* wk      = (const float*)d_in[6];
  const float* wv      = (const float*)d_in[7];
  const float* wo      = (const float*)d_in[8];
  const float* ln2_g   = (const float*)d_in[9];
  const float* ln2_b   = (const float*)d_in[10];
  const float* w1      = (const float*)d_in[11];
  const float* b1      = (const float*)d_in[12];
  const float* w2      = (const float*)d_in[13];
  const float* b2      = (const float*)d_in[14];
  const float* lnf_g   = (const float*)d_in[15];
  const float* lnf_b   = (const float*)d_in[16];
  float* out = (float*)d_out;

  char* p = (char*)d_ws;
  size_t off = 0;
  auto take = [&](size_t bytes) -> void* {
    void* r = p + off;
    off += (bytes + 255) & ~(size_t)255;
    return r;
  };
  float*  x     = (float*) take((size_t)BS * DD * 4);
  bf16_t* h     = (bf16_t*)take((size_t)BS * DD * 2);
  bf16_t* qkv   = (bf16_t*)take((size_t)BS * 3 * DD * 2);
  bf16_t* vtb   = (bf16_t*)take((size_t)BB * NHEAD * HDIM * SS * 2);
  bf16_t* ob    = (bf16_t*)take((size_t)BS * DD * 2);
  bf16_t* mid   = (bf16_t*)take((size_t)BS * DFF * 2);
  bf16_t* wqkvt = (bf16_t*)take((size_t)3 * DD * DD * 2);
  bf16_t* wot   = (bf16_t*)take((size_t)DD * DD * 2);
  bf16_t* w1t   = (bf16_t*)take((size_t)DD * DFF * 2);
  bf16_t* w2t   = (bf16_t*)take((size_t)DD * DFF * 2);
  bf16_t* te    = (bf16_t*)take((size_t)VOCAB * DD * 2);

  k_cvt<<<8192, 256, 0, stream>>>(tok_emb, te, (long)VOCAB * DD / 4);
  k_embed<<<BS, 256, 0, stream>>>(tokens, tok_emb, pos_emb, x);

  for (int l = 0; l < NLAYER; l++) {
    k_trans_all<<<12288, 256, 0, stream>>>(
        wq + (size_t)l*DD*DD, wk + (size_t)l*DD*DD, wv + (size_t)l*DD*DD,
        wo + (size_t)l*DD*DD, w1 + (size_t)l*DD*DFF, w2 + (size_t)l*DD*DFF,
        wqkvt, wot, w1t, w2t);

    k_ln<<<BS, 256, 0, stream>>>(x, ln1_g + (size_t)l*DD, ln1_b + (size_t)l*DD, h);
    k_gemm<0,false><<<dim3(16, 24), 256, 0, stream>>>(h, wqkvt, BS, 3*DD, DD,
                                                      nullptr, qkv, nullptr, nullptr);
    k_vtrans<<<BB*NHEAD*32*2, 256, 0, stream>>>(qkv, vtb);
    k_attn<<<BB*NHEAD*8, 256, 0, stream>>>(qkv, vtb, ob);
    k_gemm<1,false><<<dim3(16, 8), 256, 0, stream>>>(ob, wot, BS, DD, DD,
                                                     x, nullptr, nullptr, x);
    k_ln<<<BS, 256, 0, stream>>>(x, ln2_g + (size_t)l*DD, ln2_b + (size_t)l*DD, h);
    k_gemm<2,false><<<dim3(16, 32), 256, 0, stream>>>(h, w1t, BS, DFF, DD,
                                                      nullptr, mid, b1 + (size_t)l*DFF, nullptr);
    k_gemm<3,false><<<dim3(16, 8), 256, 0, stream>>>(mid, w2t, BS, DD, DFF,
                                                     x, nullptr, b2 + (size_t)l*DD, x);
  }
  k_ln<<<BS, 256, 0, stream>>>(x, lnf_g, lnf_b, h);
  k_gemm_logits<<<dim3(8, NBLK_LOG), 512, 0, stream>>>(h, te, out);
}